// Round 4
// baseline (8825.261 us; speedup 1.0000x reference)
//
#include <hip/hip_runtime.h>
#include <cstdint>
#include <cstddef>

typedef unsigned short ushort_t;
typedef __attribute__((ext_vector_type(8))) short short8;
typedef __attribute__((ext_vector_type(4))) float floatx4;

#define SS 128
#define BB 64
#define EE 1024
#define HH 1024
#define OO 135
#define WLW 64
#define PLP 32
#define TT 100
#define KP 160    // padded pose K (135 -> 160)
#define NWG 64    // persistent grid size (co-resident)
#define NTH 1024  // threads per wg (16 waves = 4 per SIMD)

// LDS layout (dynamic, 156672 B total)
#define WHH_PITCH 1032
#define WIH_PITCH 168
#define LDS_WHH   0              // 48 rows * 1032 * 2B = 99072
#define LDS_WIH   99072          // 48 rows * 168 * 2B  = 16128 -> 115200
// phase-B: cx (3 transposed 1024-f32 blocks) | sc | wts | part (ctx/wctx partials)
#define LDS_CX    115200         // 12288 -> 127488
#define LDS_SC    127488         // 192 f32 -> 128256
#define LDS_WTS   128256         // 192 f32 -> 129024
#define LDS_PART  129024         // 2048 f32 = 8192 -> 137216
// phase-A reduction region (disjoint from phase-B so zero-after-read persists)
// layout: [bt(4)][gate(4)][row(16) pitch 19][col(16)] f32
#define LDS_RED   137216         // 4864 f32 = 19456 -> 156672
#define RED_GATE  304            // 16 rows * pitch 19
#define RED_BT    1216           // 4 gates
#define SMEM_SZ   156672

// flagbar layout (u32 indices)
// [0]              : dtype flag
// [32 + wg*32]     : per-wg arrival phase (each on its own 128B line)
#define FB_DTYPE 0
#define FB_FLAGS 32

static __device__ __forceinline__ float bf2f(ushort_t u) {
    union { unsigned int i; float f; } v; v.i = ((unsigned int)u) << 16; return v.f;
}
static __device__ __forceinline__ ushort_t f2bf(float f) {
    union { float f; unsigned int i; } v; v.f = f;
    unsigned int x = v.i;
    x += 0x7fffu + ((x >> 16) & 1u);   // RNE
    return (ushort_t)(x >> 16);
}
static __device__ __forceinline__ float ldf(const void* p, long i, unsigned isbf) {
    if (isbf) return bf2f(((const ushort_t*)p)[i]);
    return ((const float*)p)[i];
}
static __device__ __forceinline__ short8 ldfrag(const ushort_t* p) {
    return *reinterpret_cast<const short8*>(p);
}
static __device__ __forceinline__ short8 ldfrag_l(const short* p) {
    return *reinterpret_cast<const short8*>(p);
}
// transposed-block index: element m of a 1024-block lives at (m&15)*64 + (m>>4)
// -> reader pattern cx[i*64 + lane] is bank = lane mod 32 (2-way, free)
static __device__ __forceinline__ int cxp(int m) {
    return ((m & 15) << 6) | (m >> 4);
}
// ---- system-scope (coherence-point) accessors: bypass non-coherent per-XCD L2 ----
static __device__ __forceinline__ unsigned long long sysld_u64(const void* p) {
    return __hip_atomic_load((const unsigned long long*)p, __ATOMIC_RELAXED, __HIP_MEMORY_SCOPE_SYSTEM);
}
static __device__ __forceinline__ void sysst_u16(ushort_t* p, ushort_t v) {
    __hip_atomic_store(p, v, __ATOMIC_RELAXED, __HIP_MEMORY_SCOPE_SYSTEM);
}
static __device__ __forceinline__ void sysst_u32(unsigned* p, unsigned v) {
    __hip_atomic_store(p, v, __ATOMIC_RELAXED, __HIP_MEMORY_SCOPE_SYSTEM);
}
static __device__ __forceinline__ unsigned sysld_u32(const unsigned* p) {
    return __hip_atomic_load(p, __ATOMIC_RELAXED, __HIP_MEMORY_SCOPE_SYSTEM);
}
static __device__ __forceinline__ short8 sysld_frag16(const ushort_t* p) {
    union { unsigned long long u[2]; short8 s; } r;
    r.u[0] = sysld_u64(p);
    r.u[1] = sysld_u64(p + 4);
    return r.s;
}
// fragment loader from a maybe-raw (fp32) source; kcap%8==0
static __device__ __forceinline__ short8 frag_ld(const void* p, unsigned isbf,
                                                 long rowoff, int kbase, int kcap) {
    if (kbase >= kcap) {
        short8 z = {0, 0, 0, 0, 0, 0, 0, 0};
        return z;
    }
    if (isbf) return ldfrag((const ushort_t*)p + rowoff + kbase);
    const float* f = (const float*)p + rowoff + kbase;
    short8 a;
    #pragma unroll
    for (int i = 0; i < 8; ++i) a[i] = (short)f2bf(f[i]);
    return a;
}
static __device__ __forceinline__ floatx4 mfma(short8 a, short8 b, floatx4 c) {
    return __builtin_amdgcn_mfma_f32_16x16x32_bf16(a, b, c, 0, 0, 0);
}
static __device__ __forceinline__ float sigmoidf(float x) {
    x = fminf(fmaxf(x, -30.f), 30.f);
    return 1.f / (1.f + __expf(-x));
}
static __device__ __forceinline__ float tanh_f(float x) {
    x = fminf(fmaxf(x, -15.f), 15.f);
    float e = __expf(2.f * x);
    return (e - 1.f) / (e + 1.f);
}

// Device-wide barrier, decentralized, SPLIT into arrive/wait so independent
// work can overlap the barrier round-trip. Arrival: one system store to this
// wg's private 128B line. Wait: wave 0's 64 lanes poll the 64 lines with
// system loads + __all. Monotonic phases, max skew < 2 phases.
// g_arrive's __syncthreads drains each wave's vmcnt (compiler emits full
// s_waitcnt before s_barrier), so the flag store orders after this wg's
// system data stores.
static __device__ __forceinline__ void g_arrive(unsigned* flags, unsigned phase) {
    __syncthreads();
    if (threadIdx.x == 0) {
        __builtin_amdgcn_fence(__ATOMIC_RELEASE, "workgroup");   // compiler ordering only
        sysst_u32(&flags[(size_t)blockIdx.x * 32], phase);
    }
}
static __device__ __forceinline__ void g_wait(unsigned* flags, unsigned phase) {
    if (threadIdx.x < 64) {
        for (;;) {
            unsigned v = sysld_u32(&flags[(size_t)threadIdx.x * 32]);
            if (__all((int)(v >= phase))) break;
            __builtin_amdgcn_s_sleep(1);
        }
        __builtin_amdgcn_fence(__ATOMIC_ACQUIRE, "workgroup");   // compiler ordering only
    }
    __syncthreads();
}
static __device__ __forceinline__ void gbar(unsigned* flags, unsigned phase) {
    g_arrive(flags, phase);
    g_wait(flags, phase);
}

// ---------------- dtype detect + barrier init ----------------
__global__ void k_detect(const unsigned* __restrict__ enc, unsigned* __restrict__ flag)
{
    __shared__ int cnt;
    if (threadIdx.x == 0) cnt = 0;
    __syncthreads();
    unsigned w = enc[threadIdx.x];
    unsigned ef = (w >> 7) & 0xFFu;
    if (ef >= 0x70u && ef <= 0x81u) atomicAdd(&cnt, 1);
    for (int i = threadIdx.x; i < NWG * 32; i += 256)
        sysst_u32(&flag[FB_FLAGS + i], 0u);
    __syncthreads();
    if (threadIdx.x == 0)
        flag[FB_DTYPE] = (cnt >= 200) ? 1u : 0u;
}

// ---------------- prep: pack/pad/convert ----------------
__global__ void k_prep(const void* __restrict__ eh, const void* __restrict__ Wih,
                       const void* __restrict__ Wout, const void* __restrict__ pp,
                       const void* __restrict__ Whh,
                       ushort_t* __restrict__ ehcat, ushort_t* __restrict__ wih_p,
                       ushort_t* __restrict__ wout_p, ushort_t* __restrict__ pp_pad,
                       ushort_t* __restrict__ pose_pad, ushort_t* __restrict__ whh_bf,
                       const unsigned* __restrict__ flag)
{
    unsigned isbf = flag[FB_DTYPE];
    long idx = (long)blockIdx.x * 256 + threadIdx.x;
    const long n1 = BB * EE;
    const long n2 = (long)3 * HH * KP;
    const long n3f = (long)144 * 3 * HH;
    const long n4 = (long)PLP * BB * KP;
    const long n5 = (long)BB * KP;
    const long n6 = (long)3 * HH * HH;
    if (idx < n1) {
        int b = (int)(idx >> 10), r = (int)(idx & 1023);
        int c = r >> 9, jj = r & 511;
        ehcat[idx] = f2bf(ldf(eh, (long)(c * BB + b) * 512 + jj, isbf));
        return;
    }
    idx -= n1;
    if (idx < n2) {
        long row = idx / KP, k = idx % KP;
        wih_p[idx] = (k < OO) ? f2bf(ldf(Wih, row * OO + k, isbf)) : (ushort_t)0; return;
    }
    idx -= n2;
    if (idx < n3f) {
        long row = idx / (3 * HH), k = idx % (3 * HH);
        wout_p[idx] = (row < OO) ? f2bf(ldf(Wout, row * (3 * HH) + k, isbf)) : (ushort_t)0; return;
    }
    idx -= n3f;
    if (idx < n4) {
        long t = idx / (BB * KP); long rem = idx % (BB * KP);
        long b = rem / KP, k = rem % KP;
        pp_pad[idx] = (k < OO) ? f2bf(ldf(pp, (t * BB + b) * OO + k, isbf)) : (ushort_t)0; return;
    }
    idx -= n4;
    if (idx < n5) { pose_pad[idx] = 0; return; }
    idx -= n5;
    if (idx < n6) { whh_bf[idx] = f2bf(ldf(Whh, idx, isbf)); return; }
}

// ---------------- generic MFMA GEMM with maybe-raw operands (one-time uses) ----------------
__global__ void __launch_bounds__(256) k_gemm(
    const void* __restrict__ A, int a_bf16, int lda, int kcapA,
    const void* __restrict__ B, int b_bf16, int ldb, int kcapB,
    const void* __restrict__ biasRaw,
    float* __restrict__ outF, ushort_t* __restrict__ outB16,
    ushort_t* __restrict__ outHi, ushort_t* __restrict__ outLo,
    int ldo, int M, int N, int K, const unsigned* __restrict__ flag)
{
    unsigned isbf = flag[FB_DTYPE];
    unsigned a_isbf = a_bf16 ? 1u : isbf;
    unsigned b_isbf = b_bf16 ? 1u : isbf;
    int lane = threadIdx.x & 63;
    int wid = (blockIdx.x << 2) + (threadIdx.x >> 6);
    int ng = N >> 6;
    int mt = wid / ng, g = wid % ng;
    if (mt * 16 >= M) return;
    int col = lane & 15, quad = lane >> 4;
    long arow = (long)(mt * 16 + col) * lda;
    long brow0 = (long)((g << 6) + col) * ldb;
    long brow1 = brow0 + (long)16 * ldb;
    long brow2 = brow0 + (long)32 * ldb;
    long brow3 = brow0 + (long)48 * ldb;
    int kb = quad * 8;
    floatx4 ac0 = {0.f, 0.f, 0.f, 0.f}, ac1 = ac0, ac2 = ac0, ac3 = ac0;
    for (int k = 0; k < K; k += 32) {
        short8 av = frag_ld(A, a_isbf, arow, kb + k, kcapA);
        ac0 = mfma(av, frag_ld(B, b_isbf, brow0, kb + k, kcapB), ac0);
        ac1 = mfma(av, frag_ld(B, b_isbf, brow1, kb + k, kcapB), ac1);
        ac2 = mfma(av, frag_ld(B, b_isbf, brow2, kb + k, kcapB), ac2);
        ac3 = mfma(av, frag_ld(B, b_isbf, brow3, kb + k, kcapB), ac3);
    }
    int m0 = mt * 16 + quad * 4;
    #pragma unroll
    for (int tIdx = 0; tIdx < 4; ++tIdx) {
        floatx4 ac = (tIdx == 0) ? ac0 : (tIdx == 1) ? ac1 : (tIdx == 2) ? ac2 : ac3;
        int n = (g << 6) + tIdx * 16 + col;
        float bv = biasRaw ? ldf(biasRaw, n, isbf) : 0.f;
        #pragma unroll
        for (int r = 0; r < 4; ++r) {
            float v = ac[r] + bv;
            size_t o = (size_t)(m0 + r) * ldo + n;
            if (outF) outF[o] = v;
            if (outB16) outB16[o] = f2bf(v);
            if (outHi) {
                ushort_t hi = f2bf(v);
                outHi[o] = hi;
                outLo[o] = f2bf(v - bf2f(hi));
            }
        }
    }
}

// ---------------- persistent decoder: 132 steps, 1024 threads ----------------
// 16 waves per wg (4/SIMD). Phase A: GRU K-split 4-ways (wave = (bt, ks)),
// atomic LDS reduce (1 sync). The W_hh K-loop for step t+1 runs between
// arrive(bar2) and wait(bar2) -- it only needs h(t), which bar1 confirmed.
// Phase B: transposed-cx; scores via unified encP|wordP base, unroll 4;
// ctx/wctx 2-way s-split across all 1024 threads; pose unroll 3.
__global__ void __launch_bounds__(1024, 4) k_persist(
    const ushort_t* encP,    // [S*B][1024] bf16, includes b_att (read-only, L2/L3-warm)
    const ushort_t* wordP,   // [WL*B][1024] bf16 == encP + SS*BB*HH (contiguous!)
    const ushort_t* __restrict__ whh_bf, const ushort_t* __restrict__ wih_p,
    const void* __restrict__ b_ih, const void* __restrict__ b_hh,
    const ushort_t* __restrict__ wout_p,  // [144][3072] bf16
    const void* __restrict__ b_out,
    const ushort_t* __restrict__ pp_pad, ushort_t* __restrict__ pose_pad,
    float* hFa, float* hFb, ushort_t* hhia, ushort_t* hhib,
    ushort_t* hloa, ushort_t* hlob,
    void* __restrict__ out, unsigned* flagbar)
{
    extern __shared__ char smem[];
    short* whh_lds = (short*)(smem + LDS_WHH);
    short* wih_lds = (short*)(smem + LDS_WIH);
    float* cx   = (float*)(smem + LDS_CX);   // 3 transposed 1024-blocks: h | ctx | wctx
    float* sc   = (float*)(smem + LDS_SC);
    float* wts  = (float*)(smem + LDS_WTS);
    float* part = (float*)(smem + LDS_PART); // [0,1024) ctx-hi partial, [1024,2048) wctx-hi
    float* red  = (float*)(smem + LDS_RED);  // phase-A atomic partials, pitch-19 rows

    const int tid = threadIdx.x;
    const int lane = tid & 63, wv = tid >> 6;       // wv in [0,16)
    const int wg = blockIdx.x;
    const int col = lane & 15, quad = lane >> 4;
    const int bt = wv & 3;        // batch tile (16 batches)
    const int ks = wv >> 2;       // K segment  (256 of HH)
    unsigned isbf = flagbar[FB_DTYPE];
    unsigned* flags = flagbar + FB_FLAGS;
    unsigned bphase = 0;

    float* hFs = hFa; float* hFd = hFb;
    ushort_t* hhis = hhia; ushort_t* hhid = hhib;
    ushort_t* hlos = hloa; ushort_t* hlod = hlob;

    // ---- stage this wg's GRU weight slice into LDS; zero red (once) ----
    for (int s = tid; s < 48 * 128; s += NTH) {
        int r = s >> 7;
        int ko = (s & 127) << 3;
        int g = r >> 4, rr = r & 15;
        *(short8*)(whh_lds + r * WHH_PITCH + ko) =
            ldfrag(whh_bf + (size_t)g * HH * HH + (size_t)(wg * 16 + rr) * HH + ko);
    }
    for (int s = tid; s < 48 * 20; s += NTH) {
        int r = s / 20;
        int ko = (s % 20) << 3;
        int g = r >> 4, rr = r & 15;
        *(short8*)(wih_lds + r * WIH_PITCH + ko) =
            ldfrag(wih_p + (size_t)g * HH * KP + (size_t)(wg * 16 + rr) * KP + ko);
    }
    for (int i = tid; i < 4 * RED_BT; i += NTH) red[i] = 0.f;
    __syncthreads();

    const int j = wg * 16 + col;
    const float bir = ldf(b_ih, j, isbf)          + ldf(b_hh, j, isbf);
    const float biz = ldf(b_ih, HH + j, isbf)     + ldf(b_hh, HH + j, isbf);
    const float bin = ldf(b_ih, 2 * HH + j, isbf);
    const float bhn = ldf(b_hh, 2 * HH + j, isbf);

    // W_hh-part pointers (loop-invariant)
    const short* w0 = whh_lds + (size_t)(0  + col) * WHH_PITCH + quad * 8;
    const short* w1 = whh_lds + (size_t)(16 + col) * WHH_PITCH + quad * 8;
    const short* w2 = whh_lds + (size_t)(32 + col) * WHH_PITCH + quad * 8;
    const short* c0 = wih_lds + (size_t)(0  + col) * WIH_PITCH + quad * 8;
    const short* c1 = wih_lds + (size_t)(16 + col) * WIH_PITCH + quad * 8;
    const short* c2 = wih_lds + (size_t)(32 + col) * WIH_PITCH + quad * 8;
    const int k0 = ks * 256, k1 = k0 + 256;

    // persistent partials for the overlapped W_hh K-loop
    floatx4 pR = {0.f, 0.f, 0.f, 0.f}, pZ = pR, pNh = pR;

    // part1: pR/pZ/pNh += W_hh-slice . h  (reads hhis/hlos = current h state)
    auto part1 = [&]() {
        const ushort_t* ah = hhis + (size_t)(bt * 16 + col) * HH + quad * 8;
        const ushort_t* al = hlos + (size_t)(bt * 16 + col) * HH + quad * 8;
        #pragma unroll 4
        for (int k = k0; k < k1; k += 32) {
            short8 f0 = ldfrag_l(w0 + k), f1 = ldfrag_l(w1 + k), f2 = ldfrag_l(w2 + k);
            short8 xh = sysld_frag16(ah + k), xl = sysld_frag16(al + k);
            pR = mfma(xh, f0, pR);   pR = mfma(xl, f0, pR);
            pZ = mfma(xh, f1, pZ);   pZ = mfma(xl, f1, pZ);
            pNh = mfma(xh, f2, pNh); pNh = mfma(xl, f2, pNh);
        }
    };

    for (int t = 0; t < PLP + TT; ++t) {
        const bool dec = (t >= PLP);
        const bool warm_src = (t <= PLP);
        const ushort_t* poseA = (t < PLP)  ? (pp_pad + (size_t)t * BB * KP)
                              : (t == PLP) ? (pp_pad + (size_t)(PLP - 1) * BB * KP)
                                           : pose_pad;
        // ======== phase A ========
        {
            if (t <= PLP) part1();   // decode steps t>PLP: computed during bar2 wait
            floatx4 aR = pR, aZ = pZ, aNh = pNh, aNi = {0.f, 0.f, 0.f, 0.f};
            pR = aNi; pZ = aNi; pNh = aNi;   // reset for next overlap round
            const ushort_t* ap = poseA + (size_t)(bt * 16 + col) * KP + quad * 8;
            for (int k5 = ks; k5 < 5; k5 += 4) {
                int k = k5 * 32;
                short8 xp = warm_src ? ldfrag(ap + k) : sysld_frag16(ap + k);
                aR = mfma(xp, ldfrag_l(c0 + k), aR);
                aZ = mfma(xp, ldfrag_l(c1 + k), aZ);
                aNi = mfma(xp, ldfrag_l(c2 + k), aNi);
            }
            // ---- K-split reduce: ks1..3 atomically add into red; ks0 reads+zeros ----
            if (ks != 0) {
                float* dst = red + bt * RED_BT;
                #pragma unroll
                for (int r = 0; r < 4; ++r) {
                    int idx = (quad * 4 + r) * 19 + col;
                    atomicAdd(&dst[idx], aR[r]);
                    atomicAdd(&dst[RED_GATE + idx], aZ[r]);
                    atomicAdd(&dst[2 * RED_GATE + idx], aNh[r]);
                    atomicAdd(&dst[3 * RED_GATE + idx], aNi[r]);
                }
            }
            __syncthreads();
            if (ks == 0) {
                float* sp = red + bt * RED_BT;
                #pragma unroll
                for (int r = 0; r < 4; ++r) {
                    int idx = (quad * 4 + r) * 19 + col;
                    aR[r] += sp[idx];                  sp[idx] = 0.f;
                    aZ[r] += sp[RED_GATE + idx];       sp[RED_GATE + idx] = 0.f;
                    aNh[r] += sp[2 * RED_GATE + idx];  sp[2 * RED_GATE + idx] = 0.f;
                    aNi[r] += sp[3 * RED_GATE + idx];  sp[3 * RED_GATE + idx] = 0.f;
                }
                #pragma unroll
                for (int r = 0; r < 4; ++r) {
                    int b = bt * 16 + quad * 4 + r;
                    float hold = hFs[(size_t)b * HH + j];
                    float rg = sigmoidf(aR[r] + bir);
                    float zg = sigmoidf(aZ[r] + biz);
                    float ng = tanh_f(aNi[r] + bin + rg * (aNh[r] + bhn));
                    float hn = (1.f - zg) * ng + zg * hold;
                    hFd[(size_t)b * HH + j] = hn;                 // wg-private across steps
                    ushort_t hi = f2bf(hn);
                    sysst_u16(&hhid[(size_t)b * HH + j], hi);     // cross-wg -> coherence point
                    sysst_u16(&hlod[(size_t)b * HH + j], f2bf(hn - bf2f(hi)));
                }
            }
        }
        { float* tf = hFs; hFs = hFd; hFd = tf; }
        { ushort_t* tp = hhis; hhis = hhid; hhid = tp;
          tp = hlos; hlos = hlod; hlod = tp; }
        ++bphase;
        gbar(flags, bphase);
        if (!dec) continue;

        // ======== phase B: scores + softmax + ctx/wctx + pose (wg = batch) ========
        {
            const int b = wg;
            // h = hi + lo -> transposed block 0 (4 scalar stores, 4-way max)
            if (tid < 256) {
                union { unsigned long long u; ushort_t e[4]; } h4, l4;
                h4.u = sysld_u64(hhis + (size_t)b * HH + tid * 4);
                l4.u = sysld_u64(hlos + (size_t)b * HH + tid * 4);
                #pragma unroll
                for (int i = 0; i < 4; ++i)
                    cx[cxp(tid * 4 + i)] = bf2f(h4.e[i]) + bf2f(l4.e[i]);
            }
            __syncthreads();
            // hoist this lane's h-slice: cx[i*64 + lane] -> bank = lane mod 32 (free)
            float hreg[16];
            #pragma unroll
            for (int i = 0; i < 16; ++i) hreg[i] = cx[(i << 6) | lane];
            // scores: wordP == encP + SS*BB*HH, so one branch-free base covers 192 rows
            const ushort_t* rows = encP;
            #pragma unroll 4
            for (int idx = wv; idx < 192; idx += 16) {   // 12 rows per wave
                const ushort_t* rp = rows + ((size_t)(idx * BB + b) << 10);
                short8 v0 = ldfrag(rp + lane * 16);
                short8 v1 = ldfrag(rp + lane * 16 + 8);
                float s = 0.f;
                #pragma unroll
                for (int i = 0; i < 8; ++i) s += bf2f((ushort_t)v0[i]) * hreg[i];
                #pragma unroll
                for (int i = 0; i < 8; ++i) s += bf2f((ushort_t)v1[i]) * hreg[8 + i];
                #pragma unroll
                for (int m = 1; m < 64; m <<= 1) s += __shfl_xor(s, m);
                if (lane == 0) sc[idx] = s;
            }
            __syncthreads();
            if (wv == 0) {
                float a = sc[lane], c = sc[lane + 64];
                float mx = fmaxf(a, c);
                #pragma unroll
                for (int m = 1; m < 64; m <<= 1) mx = fmaxf(mx, __shfl_xor(mx, m));
                float e0 = __expf(a - mx), e1 = __expf(c - mx);
                float sm = e0 + e1;
                #pragma unroll
                for (int m = 1; m < 64; m <<= 1) sm += __shfl_xor(sm, m);
                float inv = 1.f / sm;
                wts[lane] = e0 * inv; wts[lane + 64] = e1 * inv;
            } else if (wv == 1) {
                float a = sc[128 + lane];
                float mx = a;
                #pragma unroll
                for (int m = 1; m < 64; m <<= 1) mx = fmaxf(mx, __shfl_xor(mx, m));
                float e0 = __expf(a - mx);
                float sm = e0;
                #pragma unroll
                for (int m = 1; m < 64; m <<= 1) sm += __shfl_xor(sm, m);
                wts[128 + lane] = e0 / sm;
            }
            __syncthreads();
            // ctx: threads 0..511 (2-way s-split); wctx: threads 512..1023 (2-way)
            if (tid < 512) {
                int tt = tid & 255, sg = tid >> 8;
                float a0 = 0.f, a1 = 0.f, a2 = 0.f, a3 = 0.f;
                const ushort_t* basep = encP + ((size_t)b << 10) + tt * 4
                                        + (((size_t)(sg * 64 * BB)) << 10);
                const float* wp = wts + sg * 64;
                #pragma unroll 8
                for (int s = 0; s < 64; ++s) {
                    float w = wp[s];
                    union { unsigned long long u; ushort_t e[4]; } v;
                    v.u = *(const unsigned long long*)(basep + ((size_t)(s * BB) << 10));
                    a0 += w * bf2f(v.e[0]); a1 += w * bf2f(v.e[1]);
                    a2 += w * bf2f(v.e[2]); a3 += w * bf2f(v.e[3]);
                }
                if (sg == 0) {
                    cx[1024 + cxp(tt * 4 + 0)] = a0; cx[1024 + cxp(tt * 4 + 1)] = a1;
                    cx[1024 + cxp(tt * 4 + 2)] = a2; cx[1024 + cxp(tt * 4 + 3)] = a3;
                } else {
                    part[cxp(tt * 4 + 0)] = a0; part[cxp(tt * 4 + 1)] = a1;
                    part[cxp(tt * 4 + 2)] = a2; part[cxp(tt * 4 + 3)] = a3;
                }
            } else {
                int tt = tid & 255, sg = (tid >> 8) - 2;
                float a0 = 0.f, a1 = 0.f, a2 = 0.f, a3 = 0.f;
                const ushort_t* basep = wordP + ((size_t)b << 10) + tt * 4
                                        + (((size_t)(sg * 32 * BB)) << 10);
                const float* wp = wts + 128 + sg * 32;
                #pragma unroll 8
                for (int s = 0; s < 32; ++s) {
                    float w = wp[s];
                    union { unsigned long long u; ushort_t e[4]; } v;
                    v.u = *(const unsigned long long*)(basep + ((size_t)(s * BB) << 10));
                    a0 += w * bf2f(v.e[0]); a1 += w * bf2f(v.e[1]);
                    a2 += w * bf2f(v.e[2]); a3 += w * bf2f(v.e[3]);
                }
                if (sg == 0) {
                    cx[2048 + cxp(tt * 4 + 0)] = a0; cx[2048 + cxp(tt * 4 + 1)] = a1;
                    cx[2048 + cxp(tt * 4 + 2)] = a2; cx[2048 + cxp(tt * 4 + 3)] = a3;
                } else {
                    part[1024 + cxp(tt * 4 + 0)] = a0; part[1024 + cxp(tt * 4 + 1)] = a1;
                    part[1024 + cxp(tt * 4 + 2)] = a2; part[1024 + cxp(tt * 4 + 3)] = a3;
                }
            }
            __syncthreads();
            if (tid < 256) {
                #pragma unroll
                for (int i = 0; i < 4; ++i)
                    cx[1024 + cxp(tid * 4 + i)] += part[cxp(tid * 4 + i)];
            } else if (tid < 512) {
                int tt = tid - 256;
                #pragma unroll
                for (int i = 0; i < 4; ++i)
                    cx[2048 + cxp(tt * 4 + i)] += part[1024 + cxp(tt * 4 + i)];
            }
            __syncthreads();
            // pose: chunked mapping -- lane handles elems c*1024 + lane*16 + i
            float cr[48];
            #pragma unroll
            for (int c3 = 0; c3 < 3; ++c3)
                #pragma unroll
                for (int i = 0; i < 16; ++i)
                    cr[c3 * 16 + i] = cx[c3 * 1024 + (i << 6) + lane];
            int td = t - PLP;
            #pragma unroll 3
            for (int oo = 0; oo < 9; ++oo) {
                int o = wv * 9 + oo;   // 0..143
                const ushort_t* wr = wout_p + (size_t)o * (3 * HH) + lane * 16;
                float s = 0.f;
                #pragma unroll
                for (int c3 = 0; c3 < 3; ++c3) {
                    short8 w8a = ldfrag(wr + c3 * 1024);
                    short8 w8b = ldfrag(wr + c3 * 1024 + 8);
                    #pragma unroll
                    for (int i = 0; i < 8; ++i) s += bf2f((ushort_t)w8a[i]) * cr[c3 * 16 + i];
                    #pragma unroll
                    for (int i = 0; i < 8; ++i) s += bf2f((ushort_t)w8b[i]) * cr[c3 * 16 + 8 + i];
                }
                #pragma unroll
                for (int m = 1; m < 64; m <<= 1) s += __shfl_xor(s, m);
                if (lane == 0) {
                    float v = s + ((o < OO) ? ldf(b_out, o, isbf) : 0.f);
                    if (o < OO) {
                        size_t oi = ((size_t)td * BB + b) * OO + o;
                        if (isbf) ((ushort_t*)out)[oi] = f2bf(v);
                        else      ((float*)out)[oi] = v;
                    }
                    sysst_u16(&pose_pad[(size_t)b * KP + o], (o < OO) ? f2bf(v) : (ushort_t)0);
                }
            }
        }
        ++bphase;
        g_arrive(flags, bphase);
        // Overlap bar2 round-trip with next step's W_hh.h(t) K-loop:
        // h(t) was published and CONFIRMED at bar1 of this step, so reading it
        // here (before other wgs pass bar2) is race-free. pose-dependent work
        // (part2) stays after g_wait.
        if (t + 1 < PLP + TT) part1();
        g_wait(flags, bphase);
    }
}

extern "C" void kernel_launch(void* const* d_in, const int* in_sizes, int n_in,
                              void* d_out, int out_size, void* d_ws, size_t ws_size,
                              hipStream_t stream)
{
    (void)in_sizes; (void)n_in; (void)out_size; (void)ws_size;
    const void* enc_states = d_in[0];
    const void* enc_hidden = d_in[1];
    const void* prev_poses = d_in[2];
    const void* words      = d_in[3];
    const void* W_ed  = d_in[5];
    const void* b_ed  = d_in[6];
    const void* W_att = d_in[7];
    const void* b_att = d_in[8];
    const void* W_watt = d_in[9];
    const void* b_watt = d_in[10];
    const void* W_ih  = d_in[11];
    const void* W_hh  = d_in[12];
    const void* b_ih  = d_in[13];
    const void* b_hh  = d_in[14];
    const void* W_out = d_in[15];
    const void* b_out = d_in[16];

    char* base = (char*)d_ws;
    size_t off = 0;
    auto alloc = [&](size_t bytes) -> char* {
        char* p = base + off;
        off = (off + bytes + 255) & ~(size_t)255;
        return p;
    };
    unsigned* flagbar  = (unsigned*)alloc(128 + (size_t)NWG * 128);  // dtype line + 64 flag lines
    ushort_t* ehcat    = (ushort_t*)alloc((size_t)BB * EE * 2);
    ushort_t* wih_p    = (ushort_t*)alloc((size_t)3 * HH * KP * 2);
    ushort_t* wout_p   = (ushort_t*)alloc((size_t)144 * 3 * HH * 2);
    ushort_t* pp_pad   = (ushort_t*)alloc((size_t)PLP * BB * KP * 2);
    ushort_t* pose_pad = (ushort_t*)alloc((size_t)BB * KP * 2);
    ushort_t* whh_bf   = (ushort_t*)alloc((size_t)3 * HH * HH * 2);
    float*    hF0      = (float*)alloc((size_t)BB * HH * 4);
    float*    hF1      = (float*)alloc((size_t)BB * HH * 4);
    ushort_t* hhi0     = (ushort_t*)alloc((size_t)BB * HH * 2);
    ushort_t* hhi1     = (ushort_t*)alloc((size_t)BB * HH * 2);
    ushort_t* hlo0     = (ushort_t*)alloc((size_t)BB * HH * 2);
    ushort_t* hlo1     = (ushort_t*)alloc((size_t)BB * HH * 2);
    // encP then wordP MUST stay adjacent: k_persist's score loop indexes both
    // through one base pointer (16 MiB encP block is 256-aligned, so wordP
    // lands exactly at encP + SS*BB*HH elements).
    ushort_t* encP     = (ushort_t*)alloc((size_t)SS * BB * HH * 2);
    ushort_t* wordP    = (ushort_t*)alloc((size_t)WLW * BB * HH * 2);

    k_detect<<<1, 256, 0, stream>>>((const unsigned*)enc_states, flagbar);

    k_prep<<<17512, 256, 0, stream>>>(enc_hidden, W_ih, W_out, prev_poses, W_hh,
                                      ehcat, wih_p, wout_p, pp_pad, pose_pad, whh_bf,
                                      flagbar);

    // h0 = ehcat @ W_ed^T + b_ed
    k_gemm<<<16, 256, 0, stream>>>(ehcat, 1, EE, EE, W_ed, 0, EE, EE, b_ed,
                                   hF0, nullptr, hhi0, hlo0, HH, BB, HH, EE, flagbar);
    // encP = enc @ W_att^T + b_att
    k_gemm<<<2048, 256, 0, stream>>>(enc_states, 0, EE, EE, W_att, 0, EE, EE, b_att,
                                     nullptr, encP, nullptr, nullptr, HH, SS * BB, HH, EE, flagbar);
    // wordP = words @ W_watt^T + b_watt
    k_gemm<<<1024, 256, 0, stream>>>(words, 0, 200, 200, W_watt, 0, 200, 200, b_watt,
                                     nullptr, wordP, nullptr, nullptr, HH, WLW * BB, HH, 224, flagbar);

    (void)hipFuncSetAttribute((const void*)k_persist,
                              hipFuncAttributeMaxDynamicSharedMemorySize, SMEM_SZ);
    k_persist<<<NWG, NTH, SMEM_SZ, stream>>>(encP, wordP, whh_bf, wih_p,
                                             b_ih, b_hh, wout_p, b_out, pp_pad, pose_pad,
                                             hF0, hF1, hhi0, hhi1, hlo0, hlo1,
                                             d_out, flagbar);
}

// Round 7
// 6131.234 us; speedup vs baseline: 1.4394x; 1.4394x over previous
//
#include <hip/hip_runtime.h>
#include <cstdint>
#include <cstddef>

typedef unsigned short ushort_t;
typedef __attribute__((ext_vector_type(8))) short short8;
typedef __attribute__((ext_vector_type(4))) float floatx4;

#define SS 128
#define BB 64
#define EE 1024
#define HH 1024
#define OO 135
#define WLW 64
#define PLP 32
#define TT 100
#define KP 160    // padded pose K (135 -> 160)
#define NWG 64    // persistent grid size (co-resident)
#define NTH 1024  // threads per wg (16 waves = 4 per SIMD)

// LDS layout (dynamic, 154112 B total)
#define WHH_PITCH 1032
#define WIH_PITCH 168
#define LDS_WHH   0              // 48 rows * 1032 * 2B = 99072
#define LDS_WIH   99072          // 48 rows * 168 * 2B  = 16128 -> 115200
// phase-B region: cx (3 blocks x 1024 f32, TRANSPOSED within block) | sc | wts
#define LDS_CX    115200         // 12288 -> 127488
#define LDS_SC    127488         // 192 f32 -> 128256
#define LDS_WTS   128256         // 192 f32 -> 129024
// phase-A region overlaps phase-B region (time-disjoint): K-split partials
// layout: [reg(2)][bt(4)][gate(4)][row(16) pitch 19][col(16)] f32
#define LDS_RED   115200         // 2*4*4*304*4 = 38912 -> 154112
#define RED_GATE  304            // 16 rows * pitch 19
#define RED_BT    1216           // 4 gates
#define RED_REG   4864           // 4 bt

// flagbar layout (u32 indices)
// [0]              : dtype flag
// [32 + wg*32]     : per-wg arrival phase (each on its own 128B line)
#define FB_DTYPE 0
#define FB_FLAGS 32

static __device__ __forceinline__ float bf2f(ushort_t u) {
    union { unsigned int i; float f; } v; v.i = ((unsigned int)u) << 16; return v.f;
}
static __device__ __forceinline__ ushort_t f2bf(float f) {
    union { float f; unsigned int i; } v; v.f = f;
    unsigned int x = v.i;
    x += 0x7fffu + ((x >> 16) & 1u);   // RNE
    return (ushort_t)(x >> 16);
}
static __device__ __forceinline__ float ldf(const void* p, long i, unsigned isbf) {
    if (isbf) return bf2f(((const ushort_t*)p)[i]);
    return ((const float*)p)[i];
}
static __device__ __forceinline__ short8 ldfrag(const ushort_t* p) {
    return *reinterpret_cast<const short8*>(p);
}
static __device__ __forceinline__ short8 ldfrag_l(const short* p) {
    return *reinterpret_cast<const short8*>(p);
}
// transposed-block index: element m of a 1024-block lives at (m&15)*64 + (m>>4)
// -> reader pattern cx[i*64 + lane] is bank = lane mod 32 (2-way, free)
static __device__ __forceinline__ int cxp(int m) {
    return ((m & 15) << 6) | (m >> 4);
}
// ---- system-scope (coherence-point) accessors: bypass non-coherent per-XCD L2 ----
static __device__ __forceinline__ unsigned long long sysld_u64(const void* p) {
    return __hip_atomic_load((const unsigned long long*)p, __ATOMIC_RELAXED, __HIP_MEMORY_SCOPE_SYSTEM);
}
static __device__ __forceinline__ void sysst_u16(ushort_t* p, ushort_t v) {
    __hip_atomic_store(p, v, __ATOMIC_RELAXED, __HIP_MEMORY_SCOPE_SYSTEM);
}
static __device__ __forceinline__ void sysst_u32(unsigned* p, unsigned v) {
    __hip_atomic_store(p, v, __ATOMIC_RELAXED, __HIP_MEMORY_SCOPE_SYSTEM);
}
static __device__ __forceinline__ unsigned sysld_u32(const unsigned* p) {
    return __hip_atomic_load(p, __ATOMIC_RELAXED, __HIP_MEMORY_SCOPE_SYSTEM);
}
static __device__ __forceinline__ short8 sysld_frag16(const ushort_t* p) {
    union { unsigned long long u[2]; short8 s; } r;
    r.u[0] = sysld_u64(p);
    r.u[1] = sysld_u64(p + 4);
    return r.s;
}
// fragment loader from a maybe-raw (fp32) source; kcap%8==0
static __device__ __forceinline__ short8 frag_ld(const void* p, unsigned isbf,
                                                 long rowoff, int kbase, int kcap) {
    if (kbase >= kcap) {
        short8 z = {0, 0, 0, 0, 0, 0, 0, 0};
        return z;
    }
    if (isbf) return ldfrag((const ushort_t*)p + rowoff + kbase);
    const float* f = (const float*)p + rowoff + kbase;
    short8 a;
    #pragma unroll
    for (int i = 0; i < 8; ++i) a[i] = (short)f2bf(f[i]);
    return a;
}
static __device__ __forceinline__ floatx4 mfma(short8 a, short8 b, floatx4 c) {
    return __builtin_amdgcn_mfma_f32_16x16x32_bf16(a, b, c, 0, 0, 0);
}
static __device__ __forceinline__ float sigmoidf(float x) {
    x = fminf(fmaxf(x, -30.f), 30.f);
    return 1.f / (1.f + __expf(-x));
}
static __device__ __forceinline__ float tanh_f(float x) {
    x = fminf(fmaxf(x, -15.f), 15.f);
    float e = __expf(2.f * x);
    return (e - 1.f) / (e + 1.f);
}

// Device-wide barrier, decentralized (see R0/R1 notes). Arrival: one system
// store to this wg's private 128B line. Wait: wave 0's 64 lanes poll the 64
// lines with system loads + __all. Monotonic phases, max skew < 2 phases.
static __device__ __forceinline__ void gbar(unsigned* flags, unsigned phase) {
    __syncthreads();
    if (threadIdx.x < 64) {
        __builtin_amdgcn_fence(__ATOMIC_RELEASE, "workgroup");   // compiler ordering only
        if (threadIdx.x == 0)
            sysst_u32(&flags[(size_t)blockIdx.x * 32], phase);
        for (;;) {
            unsigned v = sysld_u32(&flags[(size_t)threadIdx.x * 32]);
            if (__all((int)(v >= phase))) break;
            __builtin_amdgcn_s_sleep(1);
        }
        __builtin_amdgcn_fence(__ATOMIC_ACQUIRE, "workgroup");   // compiler ordering only
    }
    __syncthreads();
}

// ---------------- dtype detect + barrier init ----------------
__global__ void k_detect(const unsigned* __restrict__ enc, unsigned* __restrict__ flag)
{
    __shared__ int cnt;
    if (threadIdx.x == 0) cnt = 0;
    __syncthreads();
    unsigned w = enc[threadIdx.x];
    unsigned ef = (w >> 7) & 0xFFu;
    if (ef >= 0x70u && ef <= 0x81u) atomicAdd(&cnt, 1);
    for (int i = threadIdx.x; i < NWG * 32; i += 256)
        sysst_u32(&flag[FB_FLAGS + i], 0u);
    __syncthreads();
    if (threadIdx.x == 0)
        flag[FB_DTYPE] = (cnt >= 200) ? 1u : 0u;
}

// ---------------- prep: pack/pad/convert ----------------
__global__ void k_prep(const void* __restrict__ eh, const void* __restrict__ Wih,
                       const void* __restrict__ Wout, const void* __restrict__ pp,
                       const void* __restrict__ Whh,
                       ushort_t* __restrict__ ehcat, ushort_t* __restrict__ wih_p,
                       ushort_t* __restrict__ wout_p, ushort_t* __restrict__ pp_pad,
                       ushort_t* __restrict__ pose_pad, ushort_t* __restrict__ whh_bf,
                       const unsigned* __restrict__ flag)
{
    unsigned isbf = flag[FB_DTYPE];
    long idx = (long)blockIdx.x * 256 + threadIdx.x;
    const long n1 = BB * EE;
    const long n2 = (long)3 * HH * KP;
    const long n3f = (long)144 * 3 * HH;
    const long n4 = (long)PLP * BB * KP;
    const long n5 = (long)BB * KP;
    const long n6 = (long)3 * HH * HH;
    if (idx < n1) {
        int b = (int)(idx >> 10), r = (int)(idx & 1023);
        int c = r >> 9, jj = r & 511;
        ehcat[idx] = f2bf(ldf(eh, (long)(c * BB + b) * 512 + jj, isbf));
        return;
    }
    idx -= n1;
    if (idx < n2) {
        long row = idx / KP, k = idx % KP;
        wih_p[idx] = (k < OO) ? f2bf(ldf(Wih, row * OO + k, isbf)) : (ushort_t)0; return;
    }
    idx -= n2;
    if (idx < n3f) {
        long row = idx / (3 * HH), k = idx % (3 * HH);
        wout_p[idx] = (row < OO) ? f2bf(ldf(Wout, row * (3 * HH) + k, isbf)) : (ushort_t)0; return;
    }
    idx -= n3f;
    if (idx < n4) {
        long t = idx / (BB * KP); long rem = idx % (BB * KP);
        long b = rem / KP, k = rem % KP;
        pp_pad[idx] = (k < OO) ? f2bf(ldf(pp, (t * BB + b) * OO + k, isbf)) : (ushort_t)0; return;
    }
    idx -= n4;
    if (idx < n5) { pose_pad[idx] = 0; return; }
    idx -= n5;
    if (idx < n6) { whh_bf[idx] = f2bf(ldf(Whh, idx, isbf)); return; }
}

// ---------------- generic MFMA GEMM with maybe-raw operands (one-time uses) ----------------
__global__ void __launch_bounds__(256) k_gemm(
    const void* __restrict__ A, int a_bf16, int lda, int kcapA,
    const void* __restrict__ B, int b_bf16, int ldb, int kcapB,
    const void* __restrict__ biasRaw,
    float* __restrict__ outF, ushort_t* __restrict__ outB16,
    ushort_t* __restrict__ outHi, ushort_t* __restrict__ outLo,
    int ldo, int M, int N, int K, const unsigned* __restrict__ flag)
{
    unsigned isbf = flag[FB_DTYPE];
    unsigned a_isbf = a_bf16 ? 1u : isbf;
    unsigned b_isbf = b_bf16 ? 1u : isbf;
    int lane = threadIdx.x & 63;
    int wid = (blockIdx.x << 2) + (threadIdx.x >> 6);
    int ng = N >> 6;
    int mt = wid / ng, g = wid % ng;
    if (mt * 16 >= M) return;
    int col = lane & 15, quad = lane >> 4;
    long arow = (long)(mt * 16 + col) * lda;
    long brow0 = (long)((g << 6) + col) * ldb;
    long brow1 = brow0 + (long)16 * ldb;
    long brow2 = brow0 + (long)32 * ldb;
    long brow3 = brow0 + (long)48 * ldb;
    int kb = quad * 8;
    floatx4 ac0 = {0.f, 0.f, 0.f, 0.f}, ac1 = ac0, ac2 = ac0, ac3 = ac0;
    for (int k = 0; k < K; k += 32) {
        short8 av = frag_ld(A, a_isbf, arow, kb + k, kcapA);
        ac0 = mfma(av, frag_ld(B, b_isbf, brow0, kb + k, kcapB), ac0);
        ac1 = mfma(av, frag_ld(B, b_isbf, brow1, kb + k, kcapB), ac1);
        ac2 = mfma(av, frag_ld(B, b_isbf, brow2, kb + k, kcapB), ac2);
        ac3 = mfma(av, frag_ld(B, b_isbf, brow3, kb + k, kcapB), ac3);
    }
    int m0 = mt * 16 + quad * 4;
    #pragma unroll
    for (int tIdx = 0; tIdx < 4; ++tIdx) {
        floatx4 ac = (tIdx == 0) ? ac0 : (tIdx == 1) ? ac1 : (tIdx == 2) ? ac2 : ac3;
        int n = (g << 6) + tIdx * 16 + col;
        float bv = biasRaw ? ldf(biasRaw, n, isbf) : 0.f;
        #pragma unroll
        for (int r = 0; r < 4; ++r) {
            float v = ac[r] + bv;
            size_t o = (size_t)(m0 + r) * ldo + n;
            if (outF) outF[o] = v;
            if (outB16) outB16[o] = f2bf(v);
            if (outHi) {
                ushort_t hi = f2bf(v);
                outHi[o] = hi;
                outLo[o] = f2bf(v - bf2f(hi));
            }
        }
    }
}

// ---------------- persistent decoder: 132 steps, 1024 threads, phases GRU | attn+pose ----------------
// 16 waves per wg (4/SIMD). Phase A: GRU K-split 4-ways (wave = (bt, ks)),
// padded LDS tree-reduce (R2-verified structure). Phase B: transposed-cx
// layout; scores via unified encP|wordP base with unroll 2 (ONLY change vs R2).
__global__ void __launch_bounds__(1024, 4) k_persist(
    const ushort_t* encP,    // [S*B][1024] bf16, includes b_att (read-only, L2/L3-warm)
    const ushort_t* wordP,   // [WL*B][1024] bf16 == encP + SS*BB*HH (contiguous!)
    const ushort_t* __restrict__ whh_bf, const ushort_t* __restrict__ wih_p,
    const void* __restrict__ b_ih, const void* __restrict__ b_hh,
    const ushort_t* __restrict__ wout_p,  // [144][3072] bf16
    const void* __restrict__ b_out,
    const ushort_t* __restrict__ pp_pad, ushort_t* __restrict__ pose_pad,
    float* hFa, float* hFb, ushort_t* hhia, ushort_t* hhib,
    ushort_t* hloa, ushort_t* hlob,
    void* __restrict__ out, unsigned* flagbar)
{
    extern __shared__ char smem[];
    short* whh_lds = (short*)(smem + LDS_WHH);
    short* wih_lds = (short*)(smem + LDS_WIH);
    float* cx  = (float*)(smem + LDS_CX);   // 3 transposed 1024-blocks: h | ctx | wctx
    float* sc  = (float*)(smem + LDS_SC);
    float* wts = (float*)(smem + LDS_WTS);
    float* red = (float*)(smem + LDS_RED);  // phase-A partials, pitch-19 rows

    const int tid = threadIdx.x;
    const int lane = tid & 63, wv = tid >> 6;       // wv in [0,16)
    const int wg = blockIdx.x;
    const int col = lane & 15, quad = lane >> 4;
    const int bt = wv & 3;        // batch tile (16 batches)
    const int ks = wv >> 2;       // K segment  (256 of HH)
    unsigned isbf = flagbar[FB_DTYPE];
    unsigned* flags = flagbar + FB_FLAGS;
    unsigned bphase = 0;

    float* hFs = hFa; float* hFd = hFb;
    ushort_t* hhis = hhia; ushort_t* hhid = hhib;
    ushort_t* hlos = hloa; ushort_t* hlod = hlob;

    // ---- stage this wg's GRU weight slice into LDS (once) ----
    for (int s = tid; s < 48 * 128; s += NTH) {
        int r = s >> 7;
        int ko = (s & 127) << 3;
        int g = r >> 4, rr = r & 15;
        *(short8*)(whh_lds + r * WHH_PITCH + ko) =
            ldfrag(whh_bf + (size_t)g * HH * HH + (size_t)(wg * 16 + rr) * HH + ko);
    }
    for (int s = tid; s < 48 * 20; s += NTH) {
        int r = s / 20;
        int ko = (s % 20) << 3;
        int g = r >> 4, rr = r & 15;
        *(short8*)(wih_lds + r * WIH_PITCH + ko) =
            ldfrag(wih_p + (size_t)g * HH * KP + (size_t)(wg * 16 + rr) * KP + ko);
    }
    __syncthreads();

    const int j = wg * 16 + col;
    const float bir = ldf(b_ih, j, isbf)          + ldf(b_hh, j, isbf);
    const float biz = ldf(b_ih, HH + j, isbf)     + ldf(b_hh, HH + j, isbf);
    const float bin = ldf(b_ih, 2 * HH + j, isbf);
    const float bhn = ldf(b_hh, 2 * HH + j, isbf);

    for (int t = 0; t < PLP + TT; ++t) {
        const bool dec = (t >= PLP);
        const bool warm_src = (t <= PLP);
        const ushort_t* poseA = (t < PLP)  ? (pp_pad + (size_t)t * BB * KP)
                              : (t == PLP) ? (pp_pad + (size_t)(PLP - 1) * BB * KP)
                                           : pose_pad;
        // ======== phase A: GRU (wave = (bt, ks); weights from LDS) ========
        {
            const ushort_t* ah = hhis + (size_t)(bt * 16 + col) * HH + quad * 8;
            const ushort_t* al = hlos + (size_t)(bt * 16 + col) * HH + quad * 8;
            const short* w0 = whh_lds + (size_t)(0  + col) * WHH_PITCH + quad * 8;
            const short* w1 = whh_lds + (size_t)(16 + col) * WHH_PITCH + quad * 8;
            const short* w2 = whh_lds + (size_t)(32 + col) * WHH_PITCH + quad * 8;
            floatx4 aR = {0.f, 0.f, 0.f, 0.f}, aZ = aR, aNi = aR, aNh = aR;
            const int k0 = ks * 256, k1 = k0 + 256;
            #pragma unroll 4
            for (int k = k0; k < k1; k += 32) {
                short8 f0 = ldfrag_l(w0 + k), f1 = ldfrag_l(w1 + k), f2 = ldfrag_l(w2 + k);
                short8 xh = sysld_frag16(ah + k), xl = sysld_frag16(al + k);
                aR = mfma(xh, f0, aR);   aR = mfma(xl, f0, aR);
                aZ = mfma(xh, f1, aZ);   aZ = mfma(xl, f1, aZ);
                aNh = mfma(xh, f2, aNh); aNh = mfma(xl, f2, aNh);
            }
            const ushort_t* ap = poseA + (size_t)(bt * 16 + col) * KP + quad * 8;
            const short* c0 = wih_lds + (size_t)(0  + col) * WIH_PITCH + quad * 8;
            const short* c1 = wih_lds + (size_t)(16 + col) * WIH_PITCH + quad * 8;
            const short* c2 = wih_lds + (size_t)(32 + col) * WIH_PITCH + quad * 8;
            for (int k5 = ks; k5 < 5; k5 += 4) {
                int k = k5 * 32;
                short8 xp = warm_src ? ldfrag(ap + k) : sysld_frag16(ap + k);
                aR = mfma(xp, ldfrag_l(c0 + k), aR);
                aZ = mfma(xp, ldfrag_l(c1 + k), aZ);
                aNi = mfma(xp, ldfrag_l(c2 + k), aNi);
            }
            // ---- K-split tree reduction via LDS (ks1->ks0, ks3->ks2, ks2->ks0) ----
            // pitch-19 rows: bank = (4q + 19r + col) mod 32 -> <=2-way
            if (ks == 1 || ks == 3) {
                float* dst = red + (ks >> 1) * RED_REG + bt * RED_BT;
                #pragma unroll
                for (int r = 0; r < 4; ++r) {
                    int idx = (quad * 4 + r) * 19 + col;
                    dst[idx] = aR[r];                  dst[RED_GATE + idx] = aZ[r];
                    dst[2 * RED_GATE + idx] = aNh[r];  dst[3 * RED_GATE + idx] = aNi[r];
                }
            }
            __syncthreads();
            if (ks == 0 || ks == 2) {
                const float* sp = red + (ks >> 1) * RED_REG + bt * RED_BT;
                #pragma unroll
                for (int r = 0; r < 4; ++r) {
                    int idx = (quad * 4 + r) * 19 + col;
                    aR[r] += sp[idx];                  aZ[r] += sp[RED_GATE + idx];
                    aNh[r] += sp[2 * RED_GATE + idx];  aNi[r] += sp[3 * RED_GATE + idx];
                }
            }
            __syncthreads();
            if (ks == 2) {
                float* dst = red + bt * RED_BT;
                #pragma unroll
                for (int r = 0; r < 4; ++r) {
                    int idx = (quad * 4 + r) * 19 + col;
                    dst[idx] = aR[r];                  dst[RED_GATE + idx] = aZ[r];
                    dst[2 * RED_GATE + idx] = aNh[r];  dst[3 * RED_GATE + idx] = aNi[r];
                }
            }
            __syncthreads();
            if (ks == 0) {
                const float* sp = red + bt * RED_BT;
                #pragma unroll
                for (int r = 0; r < 4; ++r) {
                    int idx = (quad * 4 + r) * 19 + col;
                    aR[r] += sp[idx];                  aZ[r] += sp[RED_GATE + idx];
                    aNh[r] += sp[2 * RED_GATE + idx];  aNi[r] += sp[3 * RED_GATE + idx];
                }
                #pragma unroll
                for (int r = 0; r < 4; ++r) {
                    int b = bt * 16 + quad * 4 + r;
                    float hold = hFs[(size_t)b * HH + j];
                    float rg = sigmoidf(aR[r] + bir);
                    float zg = sigmoidf(aZ[r] + biz);
                    float ng = tanh_f(aNi[r] + bin + rg * (aNh[r] + bhn));
                    float hn = (1.f - zg) * ng + zg * hold;
                    hFd[(size_t)b * HH + j] = hn;                 // wg-private across steps
                    ushort_t hi = f2bf(hn);
                    sysst_u16(&hhid[(size_t)b * HH + j], hi);     // cross-wg -> coherence point
                    sysst_u16(&hlod[(size_t)b * HH + j], f2bf(hn - bf2f(hi)));
                }
            }
        }
        { float* tf = hFs; hFs = hFd; hFd = tf; }
        { ushort_t* tp = hhis; hhis = hhid; hhid = tp;
          tp = hlos; hlos = hlod; hlod = tp; }
        ++bphase;
        gbar(flags, bphase);
        if (!dec) continue;

        // ======== phase B: scores + softmax + ctx/wctx + pose (wg = batch) ========
        {
            const int b = wg;
            // h = hi + lo -> transposed block 0 (4 scalar stores, 4-way max)
            if (tid < 256) {
                union { unsigned long long u; ushort_t e[4]; } h4, l4;
                h4.u = sysld_u64(hhis + (size_t)b * HH + tid * 4);
                l4.u = sysld_u64(hlos + (size_t)b * HH + tid * 4);
                #pragma unroll
                for (int i = 0; i < 4; ++i)
                    cx[cxp(tid * 4 + i)] = bf2f(h4.e[i]) + bf2f(l4.e[i]);
            }
            __syncthreads();
            // hoist this lane's h-slice: cx[i*64 + lane] -> bank = lane mod 32 (free)
            float hreg[16];
            #pragma unroll
            for (int i = 0; i < 16; ++i) hreg[i] = cx[(i << 6) | lane];
            // scores: wordP == encP + SS*BB*HH, so one branch-free base covers 192 rows
            const ushort_t* rows = encP;
            #pragma unroll 2
            for (int idx = wv; idx < 192; idx += 16) {   // 12 rows per wave
                const ushort_t* rp = rows + ((size_t)(idx * BB + b) << 10);
                short8 v0 = ldfrag(rp + lane * 16);
                short8 v1 = ldfrag(rp + lane * 16 + 8);
                float s = 0.f;
                #pragma unroll
                for (int i = 0; i < 8; ++i) s += bf2f((ushort_t)v0[i]) * hreg[i];
                #pragma unroll
                for (int i = 0; i < 8; ++i) s += bf2f((ushort_t)v1[i]) * hreg[8 + i];
                #pragma unroll
                for (int m = 1; m < 64; m <<= 1) s += __shfl_xor(s, m);
                if (lane == 0) sc[idx] = s;
            }
            __syncthreads();
            if (wv == 0) {
                float a = sc[lane], c = sc[lane + 64];
                float mx = fmaxf(a, c);
                #pragma unroll
                for (int m = 1; m < 64; m <<= 1) mx = fmaxf(mx, __shfl_xor(mx, m));
                float e0 = __expf(a - mx), e1 = __expf(c - mx);
                float sm = e0 + e1;
                #pragma unroll
                for (int m = 1; m < 64; m <<= 1) sm += __shfl_xor(sm, m);
                float inv = 1.f / sm;
                wts[lane] = e0 * inv; wts[lane + 64] = e1 * inv;
            } else if (wv == 1) {
                float a = sc[128 + lane];
                float mx = a;
                #pragma unroll
                for (int m = 1; m < 64; m <<= 1) mx = fmaxf(mx, __shfl_xor(mx, m));
                float e0 = __expf(a - mx);
                float sm = e0;
                #pragma unroll
                for (int m = 1; m < 64; m <<= 1) sm += __shfl_xor(sm, m);
                wts[128 + lane] = e0 / sm;
            }
            __syncthreads();
            // ctx (threads 0..255) and wctx (threads 256..511) concurrently
            if (tid < 256) {
                float a0 = 0.f, a1 = 0.f, a2 = 0.f, a3 = 0.f;
                const ushort_t* basep = encP + ((size_t)b << 10) + tid * 4;
                #pragma unroll 8
                for (int s = 0; s < SS; ++s) {
                    float w = wts[s];
                    union { unsigned long long u; ushort_t e[4]; } v;
                    v.u = *(const unsigned long long*)(basep + ((size_t)(s * BB) << 10));
                    a0 += w * bf2f(v.e[0]); a1 += w * bf2f(v.e[1]);
                    a2 += w * bf2f(v.e[2]); a3 += w * bf2f(v.e[3]);
                }
                cx[1024 + cxp(tid * 4 + 0)] = a0; cx[1024 + cxp(tid * 4 + 1)] = a1;
                cx[1024 + cxp(tid * 4 + 2)] = a2; cx[1024 + cxp(tid * 4 + 3)] = a3;
            } else if (tid < 512) {
                int tt = tid - 256;
                float a0 = 0.f, a1 = 0.f, a2 = 0.f, a3 = 0.f;
                const ushort_t* basep = wordP + ((size_t)b << 10) + tt * 4;
                #pragma unroll 8
                for (int s = 0; s < WLW; ++s) {
                    float w = wts[128 + s];
                    union { unsigned long long u; ushort_t e[4]; } v;
                    v.u = *(const unsigned long long*)(basep + ((size_t)(s * BB) << 10));
                    a0 += w * bf2f(v.e[0]); a1 += w * bf2f(v.e[1]);
                    a2 += w * bf2f(v.e[2]); a3 += w * bf2f(v.e[3]);
                }
                cx[2048 + cxp(tt * 4 + 0)] = a0; cx[2048 + cxp(tt * 4 + 1)] = a1;
                cx[2048 + cxp(tt * 4 + 2)] = a2; cx[2048 + cxp(tt * 4 + 3)] = a3;
            }
            __syncthreads();
            // pose: chunked mapping -- lane handles elems c*1024 + lane*16 + i
            // (cx reads conflict-free via transposed blocks; W_out reads coalesced)
            float cr[48];
            #pragma unroll
            for (int c3 = 0; c3 < 3; ++c3)
                #pragma unroll
                for (int i = 0; i < 16; ++i)
                    cr[c3 * 16 + i] = cx[c3 * 1024 + (i << 6) + lane];
            int td = t - PLP;
            for (int oo = 0; oo < 9; ++oo) {
                int o = wv * 9 + oo;   // 0..143
                const ushort_t* wr = wout_p + (size_t)o * (3 * HH) + lane * 16;
                float s = 0.f;
                #pragma unroll
                for (int c3 = 0; c3 < 3; ++c3) {
                    short8 w8a = ldfrag(wr + c3 * 1024);
                    short8 w8b = ldfrag(wr + c3 * 1024 + 8);
                    #pragma unroll
                    for (int i = 0; i < 8; ++i) s += bf2f((ushort_t)w8a[i]) * cr[c3 * 16 + i];
                    #pragma unroll
                    for (int i = 0; i < 8; ++i) s += bf2f((ushort_t)w8b[i]) * cr[c3 * 16 + 8 + i];
                }
                #pragma unroll
                for (int m = 1; m < 64; m <<= 1) s += __shfl_xor(s, m);
                if (lane == 0) {
                    float v = s + ((o < OO) ? ldf(b_out, o, isbf) : 0.f);
                    if (o < OO) {
                        size_t oi = ((size_t)td * BB + b) * OO + o;
                        if (isbf) ((ushort_t*)out)[oi] = f2bf(v);
                        else      ((float*)out)[oi] = v;
                    }
                    sysst_u16(&pose_pad[(size_t)b * KP + o], (o < OO) ? f2bf(v) : (ushort_t)0);
                }
            }
        }
        ++bphase;
        gbar(flags, bphase);
    }
}

extern "C" void kernel_launch(void* const* d_in, const int* in_sizes, int n_in,
                              void* d_out, int out_size, void* d_ws, size_t ws_size,
                              hipStream_t stream)
{
    (void)in_sizes; (void)n_in; (void)out_size; (void)ws_size;
    const void* enc_states = d_in[0];
    const void* enc_hidden = d_in[1];
    const void* prev_poses = d_in[2];
    const void* words      = d_in[3];
    const void* W_ed  = d_in[5];
    const void* b_ed  = d_in[6];
    const void* W_att = d_in[7];
    const void* b_att = d_in[8];
    const void* W_watt = d_in[9];
    const void* b_watt = d_in[10];
    const void* W_ih  = d_in[11];
    const void* W_hh  = d_in[12];
    const void* b_ih  = d_in[13];
    const void* b_hh  = d_in[14];
    const void* W_out = d_in[15];
    const void* b_out = d_in[16];

    char* base = (char*)d_ws;
    size_t off = 0;
    auto alloc = [&](size_t bytes) -> char* {
        char* p = base + off;
        off = (off + bytes + 255) & ~(size_t)255;
        return p;
    };
    unsigned* flagbar  = (unsigned*)alloc(128 + (size_t)NWG * 128);  // dtype line + 64 flag lines
    ushort_t* ehcat    = (ushort_t*)alloc((size_t)BB * EE * 2);
    ushort_t* wih_p    = (ushort_t*)alloc((size_t)3 * HH * KP * 2);
    ushort_t* wout_p   = (ushort_t*)alloc((size_t)144 * 3 * HH * 2);
    ushort_t* pp_pad   = (ushort_t*)alloc((size_t)PLP * BB * KP * 2);
    ushort_t* pose_pad = (ushort_t*)alloc((size_t)BB * KP * 2);
    ushort_t* whh_bf   = (ushort_t*)alloc((size_t)3 * HH * HH * 2);
    float*    hF0      = (float*)alloc((size_t)BB * HH * 4);
    float*    hF1      = (float*)alloc((size_t)BB * HH * 4);
    ushort_t* hhi0     = (ushort_t*)alloc((size_t)BB * HH * 2);
    ushort_t* hhi1     = (ushort_t*)alloc((size_t)BB * HH * 2);
    ushort_t* hlo0     = (ushort_t*)alloc((size_t)BB * HH * 2);
    ushort_t* hlo1     = (ushort_t*)alloc((size_t)BB * HH * 2);
    // encP then wordP MUST stay adjacent: k_persist's score loop indexes both
    // through one base pointer (16 MiB encP block is 256-aligned, so wordP
    // lands exactly at encP + SS*BB*HH elements).
    ushort_t* encP     = (ushort_t*)alloc((size_t)SS * BB * HH * 2);
    ushort_t* wordP    = (ushort_t*)alloc((size_t)WLW * BB * HH * 2);

    k_detect<<<1, 256, 0, stream>>>((const unsigned*)enc_states, flagbar);

    k_prep<<<17512, 256, 0, stream>>>(enc_hidden, W_ih, W_out, prev_poses, W_hh,
                                      ehcat, wih_p, wout_p, pp_pad, pose_pad, whh_bf,
                                      flagbar);

    // h0 = ehcat @ W_ed^T + b_ed
    k_gemm<<<16, 256, 0, stream>>>(ehcat, 1, EE, EE, W_ed, 0, EE, EE, b_ed,
                                   hF0, nullptr, hhi0, hlo0, HH, BB, HH, EE, flagbar);
    // encP = enc @ W_att^T + b_att
    k_gemm<<<2048, 256, 0, stream>>>(enc_states, 0, EE, EE, W_att, 0, EE, EE, b_att,
                                     nullptr, encP, nullptr, nullptr, HH, SS * BB, HH, EE, flagbar);
    // wordP = words @ W_watt^T + b_watt
    k_gemm<<<1024, 256, 0, stream>>>(words, 0, 200, 200, W_watt, 0, 200, 200, b_watt,
                                     nullptr, wordP, nullptr, nullptr, HH, WLW * BB, HH, 224, flagbar);

    (void)hipFuncSetAttribute((const void*)k_persist,
                              hipFuncAttributeMaxDynamicSharedMemorySize, 154112);
    k_persist<<<NWG, NTH, 154112, stream>>>(encP, wordP, whh_bf, wih_p,
                                            b_ih, b_hh, wout_p, b_out, pp_pad, pose_pad,
                                            hF0, hF1, hhi0, hhi1, hlo0, hlo1,
                                            d_out, flagbar);
}

// Round 8
// 6106.334 us; speedup vs baseline: 1.4453x; 1.0041x over previous
//
#include <hip/hip_runtime.h>
#include <cstdint>
#include <cstddef>

typedef unsigned short ushort_t;
typedef __attribute__((ext_vector_type(8))) short short8;
typedef __attribute__((ext_vector_type(4))) float floatx4;

#define SS 128
#define BB 64
#define EE 1024
#define HH 1024
#define OO 135
#define WLW 64
#define PLP 32
#define TT 100
#define KP 160    // padded pose K (135 -> 160)
#define NWG 64    // persistent grid size (co-resident)
#define NTH 1024  // threads per wg (16 waves = 4 per SIMD)

// LDS layout (dynamic, 154112 B total)
#define WHH_PITCH 1032
#define WIH_PITCH 168
#define LDS_WHH   0              // 48 rows * 1032 * 2B = 99072
#define LDS_WIH   99072          // 48 rows * 168 * 2B  = 16128 -> 115200
// phase-B region: cx (3 blocks x 1024 f32, TRANSPOSED within block) | sc | wts
#define LDS_CX    115200         // 12288 -> 127488
#define LDS_SC    127488         // 192 f32 -> 128256
#define LDS_WTS   128256         // 192 f32 -> 129024
// phase-A region overlaps phase-B region (time-disjoint): K-split partials
// layout: [reg(2)][bt(4)][gate(4)][row(16) pitch 19][col(16)] f32
#define LDS_RED   115200         // 2*4*4*304*4 = 38912 -> 154112
#define RED_GATE  304            // 16 rows * pitch 19
#define RED_BT    1216           // 4 gates
#define RED_REG   4864           // 4 bt

// flagbar layout (u32 indices)
// [0]              : dtype flag
// [32 + wg*32]     : per-wg arrival phase (each on its own 128B line)
#define FB_DTYPE 0
#define FB_FLAGS 32

static __device__ __forceinline__ float bf2f(ushort_t u) {
    union { unsigned int i; float f; } v; v.i = ((unsigned int)u) << 16; return v.f;
}
static __device__ __forceinline__ ushort_t f2bf(float f) {
    union { float f; unsigned int i; } v; v.f = f;
    unsigned int x = v.i;
    x += 0x7fffu + ((x >> 16) & 1u);   // RNE
    return (ushort_t)(x >> 16);
}
static __device__ __forceinline__ float ldf(const void* p, long i, unsigned isbf) {
    if (isbf) return bf2f(((const ushort_t*)p)[i]);
    return ((const float*)p)[i];
}
static __device__ __forceinline__ short8 ldfrag(const ushort_t* p) {
    return *reinterpret_cast<const short8*>(p);
}
static __device__ __forceinline__ short8 ldfrag_l(const short* p) {
    return *reinterpret_cast<const short8*>(p);
}
// transposed-block index: element m of a 1024-block lives at (m&15)*64 + (m>>4)
// -> reader pattern cx[i*64 + lane] is bank = lane mod 32 (2-way, free)
static __device__ __forceinline__ int cxp(int m) {
    return ((m & 15) << 6) | (m >> 4);
}
// ---- AGENT-scope (device/MALL coherence-point) data accessors ----
// Cross-XCD h/pose state: AGENT scope bypasses the non-coherent per-XCD L2
// but is served at the MALL/L3 coherence point (NOT memory-side like SYSTEM
// scope) -- device-wide coherent per the HIP memory model, ~half the latency,
// and the 512KB h state stays L3-resident instead of round-tripping HBM.
static __device__ __forceinline__ unsigned long long sysld_u64(const void* p) {
    return __hip_atomic_load((const unsigned long long*)p, __ATOMIC_RELAXED, __HIP_MEMORY_SCOPE_AGENT);
}
static __device__ __forceinline__ void sysst_u16(ushort_t* p, ushort_t v) {
    __hip_atomic_store(p, v, __ATOMIC_RELAXED, __HIP_MEMORY_SCOPE_AGENT);
}
// ---- SYSTEM-scope accessors: barrier flags only (tiny traffic, max safety) ----
static __device__ __forceinline__ void sysst_u32(unsigned* p, unsigned v) {
    __hip_atomic_store(p, v, __ATOMIC_RELAXED, __HIP_MEMORY_SCOPE_SYSTEM);
}
static __device__ __forceinline__ unsigned sysld_u32(const unsigned* p) {
    return __hip_atomic_load(p, __ATOMIC_RELAXED, __HIP_MEMORY_SCOPE_SYSTEM);
}
static __device__ __forceinline__ short8 sysld_frag16(const ushort_t* p) {
    union { unsigned long long u[2]; short8 s; } r;
    r.u[0] = sysld_u64(p);
    r.u[1] = sysld_u64(p + 4);
    return r.s;
}
// fragment loader from a maybe-raw (fp32) source; kcap%8==0
static __device__ __forceinline__ short8 frag_ld(const void* p, unsigned isbf,
                                                 long rowoff, int kbase, int kcap) {
    if (kbase >= kcap) {
        short8 z = {0, 0, 0, 0, 0, 0, 0, 0};
        return z;
    }
    if (isbf) return ldfrag((const ushort_t*)p + rowoff + kbase);
    const float* f = (const float*)p + rowoff + kbase;
    short8 a;
    #pragma unroll
    for (int i = 0; i < 8; ++i) a[i] = (short)f2bf(f[i]);
    return a;
}
static __device__ __forceinline__ floatx4 mfma(short8 a, short8 b, floatx4 c) {
    return __builtin_amdgcn_mfma_f32_16x16x32_bf16(a, b, c, 0, 0, 0);
}
static __device__ __forceinline__ float sigmoidf(float x) {
    x = fminf(fmaxf(x, -30.f), 30.f);
    return 1.f / (1.f + __expf(-x));
}
static __device__ __forceinline__ float tanh_f(float x) {
    x = fminf(fmaxf(x, -15.f), 15.f);
    float e = __expf(2.f * x);
    return (e - 1.f) / (e + 1.f);
}

// Device-wide barrier, decentralized (see R0/R1 notes). Arrival: one system
// store to this wg's private 128B line. Wait: wave 0's 64 lanes poll the 64
// lines with system loads + __all. Monotonic phases, max skew < 2 phases.
// __syncthreads drains vmcnt (ALL scopes), so the flag store orders after
// this wg's agent-scope data stores; remote reader sees flag -> data is at
// the MALL -> agent-scope read observes it.
static __device__ __forceinline__ void gbar(unsigned* flags, unsigned phase) {
    __syncthreads();
    if (threadIdx.x < 64) {
        __builtin_amdgcn_fence(__ATOMIC_RELEASE, "workgroup");   // compiler ordering only
        if (threadIdx.x == 0)
            sysst_u32(&flags[(size_t)blockIdx.x * 32], phase);
        for (;;) {
            unsigned v = sysld_u32(&flags[(size_t)threadIdx.x * 32]);
            if (__all((int)(v >= phase))) break;
            __builtin_amdgcn_s_sleep(1);
        }
        __builtin_amdgcn_fence(__ATOMIC_ACQUIRE, "workgroup");   // compiler ordering only
    }
    __syncthreads();
}

// ---------------- dtype detect + barrier init ----------------
__global__ void k_detect(const unsigned* __restrict__ enc, unsigned* __restrict__ flag)
{
    __shared__ int cnt;
    if (threadIdx.x == 0) cnt = 0;
    __syncthreads();
    unsigned w = enc[threadIdx.x];
    unsigned ef = (w >> 7) & 0xFFu;
    if (ef >= 0x70u && ef <= 0x81u) atomicAdd(&cnt, 1);
    for (int i = threadIdx.x; i < NWG * 32; i += 256)
        sysst_u32(&flag[FB_FLAGS + i], 0u);
    __syncthreads();
    if (threadIdx.x == 0)
        flag[FB_DTYPE] = (cnt >= 200) ? 1u : 0u;
}

// ---------------- prep: pack/pad/convert ----------------
__global__ void k_prep(const void* __restrict__ eh, const void* __restrict__ Wih,
                       const void* __restrict__ Wout, const void* __restrict__ pp,
                       const void* __restrict__ Whh,
                       ushort_t* __restrict__ ehcat, ushort_t* __restrict__ wih_p,
                       ushort_t* __restrict__ wout_p, ushort_t* __restrict__ pp_pad,
                       ushort_t* __restrict__ pose_pad, ushort_t* __restrict__ whh_bf,
                       const unsigned* __restrict__ flag)
{
    unsigned isbf = flag[FB_DTYPE];
    long idx = (long)blockIdx.x * 256 + threadIdx.x;
    const long n1 = BB * EE;
    const long n2 = (long)3 * HH * KP;
    const long n3f = (long)144 * 3 * HH;
    const long n4 = (long)PLP * BB * KP;
    const long n5 = (long)BB * KP;
    const long n6 = (long)3 * HH * HH;
    if (idx < n1) {
        int b = (int)(idx >> 10), r = (int)(idx & 1023);
        int c = r >> 9, jj = r & 511;
        ehcat[idx] = f2bf(ldf(eh, (long)(c * BB + b) * 512 + jj, isbf));
        return;
    }
    idx -= n1;
    if (idx < n2) {
        long row = idx / KP, k = idx % KP;
        wih_p[idx] = (k < OO) ? f2bf(ldf(Wih, row * OO + k, isbf)) : (ushort_t)0; return;
    }
    idx -= n2;
    if (idx < n3f) {
        long row = idx / (3 * HH), k = idx % (3 * HH);
        wout_p[idx] = (row < OO) ? f2bf(ldf(Wout, row * (3 * HH) + k, isbf)) : (ushort_t)0; return;
    }
    idx -= n3f;
    if (idx < n4) {
        long t = idx / (BB * KP); long rem = idx % (BB * KP);
        long b = rem / KP, k = rem % KP;
        pp_pad[idx] = (k < OO) ? f2bf(ldf(pp, (t * BB + b) * OO + k, isbf)) : (ushort_t)0; return;
    }
    idx -= n4;
    if (idx < n5) { pose_pad[idx] = 0; return; }
    idx -= n5;
    if (idx < n6) { whh_bf[idx] = f2bf(ldf(Whh, idx, isbf)); return; }
}

// ---------------- generic MFMA GEMM with maybe-raw operands (one-time uses) ----------------
__global__ void __launch_bounds__(256) k_gemm(
    const void* __restrict__ A, int a_bf16, int lda, int kcapA,
    const void* __restrict__ B, int b_bf16, int ldb, int kcapB,
    const void* __restrict__ biasRaw,
    float* __restrict__ outF, ushort_t* __restrict__ outB16,
    ushort_t* __restrict__ outHi, ushort_t* __restrict__ outLo,
    int ldo, int M, int N, int K, const unsigned* __restrict__ flag)
{
    unsigned isbf = flag[FB_DTYPE];
    unsigned a_isbf = a_bf16 ? 1u : isbf;
    unsigned b_isbf = b_bf16 ? 1u : isbf;
    int lane = threadIdx.x & 63;
    int wid = (blockIdx.x << 2) + (threadIdx.x >> 6);
    int ng = N >> 6;
    int mt = wid / ng, g = wid % ng;
    if (mt * 16 >= M) return;
    int col = lane & 15, quad = lane >> 4;
    long arow = (long)(mt * 16 + col) * lda;
    long brow0 = (long)((g << 6) + col) * ldb;
    long brow1 = brow0 + (long)16 * ldb;
    long brow2 = brow0 + (long)32 * ldb;
    long brow3 = brow0 + (long)48 * ldb;
    int kb = quad * 8;
    floatx4 ac0 = {0.f, 0.f, 0.f, 0.f}, ac1 = ac0, ac2 = ac0, ac3 = ac0;
    for (int k = 0; k < K; k += 32) {
        short8 av = frag_ld(A, a_isbf, arow, kb + k, kcapA);
        ac0 = mfma(av, frag_ld(B, b_isbf, brow0, kb + k, kcapB), ac0);
        ac1 = mfma(av, frag_ld(B, b_isbf, brow1, kb + k, kcapB), ac1);
        ac2 = mfma(av, frag_ld(B, b_isbf, brow2, kb + k, kcapB), ac2);
        ac3 = mfma(av, frag_ld(B, b_isbf, brow3, kb + k, kcapB), ac3);
    }
    int m0 = mt * 16 + quad * 4;
    #pragma unroll
    for (int tIdx = 0; tIdx < 4; ++tIdx) {
        floatx4 ac = (tIdx == 0) ? ac0 : (tIdx == 1) ? ac1 : (tIdx == 2) ? ac2 : ac3;
        int n = (g << 6) + tIdx * 16 + col;
        float bv = biasRaw ? ldf(biasRaw, n, isbf) : 0.f;
        #pragma unroll
        for (int r = 0; r < 4; ++r) {
            float v = ac[r] + bv;
            size_t o = (size_t)(m0 + r) * ldo + n;
            if (outF) outF[o] = v;
            if (outB16) outB16[o] = f2bf(v);
            if (outHi) {
                ushort_t hi = f2bf(v);
                outHi[o] = hi;
                outLo[o] = f2bf(v - bf2f(hi));
            }
        }
    }
}

// ---------------- persistent decoder: 132 steps, 1024 threads, phases GRU | attn+pose ----------------
// 16 waves per wg (4/SIMD). Phase A: GRU K-split 4-ways (wave = (bt, ks)),
// padded LDS tree-reduce. Phase B: transposed-cx layout; scores via unified
// encP|wordP base with unroll 2. THIS ROUND: h/pose data accessors moved
// SYSTEM -> AGENT scope (MALL-resident instead of HBM round trips).
__global__ void __launch_bounds__(1024, 4) k_persist(
    const ushort_t* encP,    // [S*B][1024] bf16, includes b_att (read-only, L2/L3-warm)
    const ushort_t* wordP,   // [WL*B][1024] bf16 == encP + SS*BB*HH (contiguous!)
    const ushort_t* __restrict__ whh_bf, const ushort_t* __restrict__ wih_p,
    const void* __restrict__ b_ih, const void* __restrict__ b_hh,
    const ushort_t* __restrict__ wout_p,  // [144][3072] bf16
    const void* __restrict__ b_out,
    const ushort_t* __restrict__ pp_pad, ushort_t* __restrict__ pose_pad,
    float* hFa, float* hFb, ushort_t* hhia, ushort_t* hhib,
    ushort_t* hloa, ushort_t* hlob,
    void* __restrict__ out, unsigned* flagbar)
{
    extern __shared__ char smem[];
    short* whh_lds = (short*)(smem + LDS_WHH);
    short* wih_lds = (short*)(smem + LDS_WIH);
    float* cx  = (float*)(smem + LDS_CX);   // 3 transposed 1024-blocks: h | ctx | wctx
    float* sc  = (float*)(smem + LDS_SC);
    float* wts = (float*)(smem + LDS_WTS);
    float* red = (float*)(smem + LDS_RED);  // phase-A partials, pitch-19 rows

    const int tid = threadIdx.x;
    const int lane = tid & 63, wv = tid >> 6;       // wv in [0,16)
    const int wg = blockIdx.x;
    const int col = lane & 15, quad = lane >> 4;
    const int bt = wv & 3;        // batch tile (16 batches)
    const int ks = wv >> 2;       // K segment  (256 of HH)
    unsigned isbf = flagbar[FB_DTYPE];
    unsigned* flags = flagbar + FB_FLAGS;
    unsigned bphase = 0;

    float* hFs = hFa; float* hFd = hFb;
    ushort_t* hhis = hhia; ushort_t* hhid = hhib;
    ushort_t* hlos = hloa; ushort_t* hlod = hlob;

    // ---- stage this wg's GRU weight slice into LDS (once) ----
    for (int s = tid; s < 48 * 128; s += NTH) {
        int r = s >> 7;
        int ko = (s & 127) << 3;
        int g = r >> 4, rr = r & 15;
        *(short8*)(whh_lds + r * WHH_PITCH + ko) =
            ldfrag(whh_bf + (size_t)g * HH * HH + (size_t)(wg * 16 + rr) * HH + ko);
    }
    for (int s = tid; s < 48 * 20; s += NTH) {
        int r = s / 20;
        int ko = (s % 20) << 3;
        int g = r >> 4, rr = r & 15;
        *(short8*)(wih_lds + r * WIH_PITCH + ko) =
            ldfrag(wih_p + (size_t)g * HH * KP + (size_t)(wg * 16 + rr) * KP + ko);
    }
    __syncthreads();

    const int j = wg * 16 + col;
    const float bir = ldf(b_ih, j, isbf)          + ldf(b_hh, j, isbf);
    const float biz = ldf(b_ih, HH + j, isbf)     + ldf(b_hh, HH + j, isbf);
    const float bin = ldf(b_ih, 2 * HH + j, isbf);
    const float bhn = ldf(b_hh, 2 * HH + j, isbf);

    for (int t = 0; t < PLP + TT; ++t) {
        const bool dec = (t >= PLP);
        const bool warm_src = (t <= PLP);
        const ushort_t* poseA = (t < PLP)  ? (pp_pad + (size_t)t * BB * KP)
                              : (t == PLP) ? (pp_pad + (size_t)(PLP - 1) * BB * KP)
                                           : pose_pad;
        // ======== phase A: GRU (wave = (bt, ks); weights from LDS) ========
        {
            const ushort_t* ah = hhis + (size_t)(bt * 16 + col) * HH + quad * 8;
            const ushort_t* al = hlos + (size_t)(bt * 16 + col) * HH + quad * 8;
            const short* w0 = whh_lds + (size_t)(0  + col) * WHH_PITCH + quad * 8;
            const short* w1 = whh_lds + (size_t)(16 + col) * WHH_PITCH + quad * 8;
            const short* w2 = whh_lds + (size_t)(32 + col) * WHH_PITCH + quad * 8;
            floatx4 aR = {0.f, 0.f, 0.f, 0.f}, aZ = aR, aNi = aR, aNh = aR;
            const int k0 = ks * 256, k1 = k0 + 256;
            #pragma unroll 4
            for (int k = k0; k < k1; k += 32) {
                short8 f0 = ldfrag_l(w0 + k), f1 = ldfrag_l(w1 + k), f2 = ldfrag_l(w2 + k);
                short8 xh = sysld_frag16(ah + k), xl = sysld_frag16(al + k);
                aR = mfma(xh, f0, aR);   aR = mfma(xl, f0, aR);
                aZ = mfma(xh, f1, aZ);   aZ = mfma(xl, f1, aZ);
                aNh = mfma(xh, f2, aNh); aNh = mfma(xl, f2, aNh);
            }
            const ushort_t* ap = poseA + (size_t)(bt * 16 + col) * KP + quad * 8;
            const short* c0 = wih_lds + (size_t)(0  + col) * WIH_PITCH + quad * 8;
            const short* c1 = wih_lds + (size_t)(16 + col) * WIH_PITCH + quad * 8;
            const short* c2 = wih_lds + (size_t)(32 + col) * WIH_PITCH + quad * 8;
            for (int k5 = ks; k5 < 5; k5 += 4) {
                int k = k5 * 32;
                short8 xp = warm_src ? ldfrag(ap + k) : sysld_frag16(ap + k);
                aR = mfma(xp, ldfrag_l(c0 + k), aR);
                aZ = mfma(xp, ldfrag_l(c1 + k), aZ);
                aNi = mfma(xp, ldfrag_l(c2 + k), aNi);
            }
            // ---- K-split tree reduction via LDS (ks1->ks0, ks3->ks2, ks2->ks0) ----
            // pitch-19 rows: bank = (4q + 19r + col) mod 32 -> <=2-way
            if (ks == 1 || ks == 3) {
                float* dst = red + (ks >> 1) * RED_REG + bt * RED_BT;
                #pragma unroll
                for (int r = 0; r < 4; ++r) {
                    int idx = (quad * 4 + r) * 19 + col;
                    dst[idx] = aR[r];                  dst[RED_GATE + idx] = aZ[r];
                    dst[2 * RED_GATE + idx] = aNh[r];  dst[3 * RED_GATE + idx] = aNi[r];
                }
            }
            __syncthreads();
            if (ks == 0 || ks == 2) {
                const float* sp = red + (ks >> 1) * RED_REG + bt * RED_BT;
                #pragma unroll
                for (int r = 0; r < 4; ++r) {
                    int idx = (quad * 4 + r) * 19 + col;
                    aR[r] += sp[idx];                  aZ[r] += sp[RED_GATE + idx];
                    aNh[r] += sp[2 * RED_GATE + idx];  aNi[r] += sp[3 * RED_GATE + idx];
                }
            }
            __syncthreads();
            if (ks == 2) {
                float* dst = red + bt * RED_BT;
                #pragma unroll
                for (int r = 0; r < 4; ++r) {
                    int idx = (quad * 4 + r) * 19 + col;
                    dst[idx] = aR[r];                  dst[RED_GATE + idx] = aZ[r];
                    dst[2 * RED_GATE + idx] = aNh[r];  dst[3 * RED_GATE + idx] = aNi[r];
                }
            }
            __syncthreads();
            if (ks == 0) {
                const float* sp = red + bt * RED_BT;
                #pragma unroll
                for (int r = 0; r < 4; ++r) {
                    int idx = (quad * 4 + r) * 19 + col;
                    aR[r] += sp[idx];                  aZ[r] += sp[RED_GATE + idx];
                    aNh[r] += sp[2 * RED_GATE + idx];  aNi[r] += sp[3 * RED_GATE + idx];
                }
                #pragma unroll
                for (int r = 0; r < 4; ++r) {
                    int b = bt * 16 + quad * 4 + r;
                    float hold = hFs[(size_t)b * HH + j];
                    float rg = sigmoidf(aR[r] + bir);
                    float zg = sigmoidf(aZ[r] + biz);
                    float ng = tanh_f(aNi[r] + bin + rg * (aNh[r] + bhn));
                    float hn = (1.f - zg) * ng + zg * hold;
                    hFd[(size_t)b * HH + j] = hn;                 // wg-private across steps
                    ushort_t hi = f2bf(hn);
                    sysst_u16(&hhid[(size_t)b * HH + j], hi);     // cross-wg -> MALL
                    sysst_u16(&hlod[(size_t)b * HH + j], f2bf(hn - bf2f(hi)));
                }
            }
        }
        { float* tf = hFs; hFs = hFd; hFd = tf; }
        { ushort_t* tp = hhis; hhis = hhid; hhid = tp;
          tp = hlos; hlos = hlod; hlod = tp; }
        ++bphase;
        gbar(flags, bphase);
        if (!dec) continue;

        // ======== phase B: scores + softmax + ctx/wctx + pose (wg = batch) ========
        {
            const int b = wg;
            // h = hi + lo -> transposed block 0 (4 scalar stores, 4-way max)
            if (tid < 256) {
                union { unsigned long long u; ushort_t e[4]; } h4, l4;
                h4.u = sysld_u64(hhis + (size_t)b * HH + tid * 4);
                l4.u = sysld_u64(hlos + (size_t)b * HH + tid * 4);
                #pragma unroll
                for (int i = 0; i < 4; ++i)
                    cx[cxp(tid * 4 + i)] = bf2f(h4.e[i]) + bf2f(l4.e[i]);
            }
            __syncthreads();
            // hoist this lane's h-slice: cx[i*64 + lane] -> bank = lane mod 32 (free)
            float hreg[16];
            #pragma unroll
            for (int i = 0; i < 16; ++i) hreg[i] = cx[(i << 6) | lane];
            // scores: wordP == encP + SS*BB*HH, so one branch-free base covers 192 rows
            const ushort_t* rows = encP;
            #pragma unroll 2
            for (int idx = wv; idx < 192; idx += 16) {   // 12 rows per wave
                const ushort_t* rp = rows + ((size_t)(idx * BB + b) << 10);
                short8 v0 = ldfrag(rp + lane * 16);
                short8 v1 = ldfrag(rp + lane * 16 + 8);
                float s = 0.f;
                #pragma unroll
                for (int i = 0; i < 8; ++i) s += bf2f((ushort_t)v0[i]) * hreg[i];
                #pragma unroll
                for (int i = 0; i < 8; ++i) s += bf2f((ushort_t)v1[i]) * hreg[8 + i];
                #pragma unroll
                for (int m = 1; m < 64; m <<= 1) s += __shfl_xor(s, m);
                if (lane == 0) sc[idx] = s;
            }
            __syncthreads();
            if (wv == 0) {
                float a = sc[lane], c = sc[lane + 64];
                float mx = fmaxf(a, c);
                #pragma unroll
                for (int m = 1; m < 64; m <<= 1) mx = fmaxf(mx, __shfl_xor(mx, m));
                float e0 = __expf(a - mx), e1 = __expf(c - mx);
                float sm = e0 + e1;
                #pragma unroll
                for (int m = 1; m < 64; m <<= 1) sm += __shfl_xor(sm, m);
                float inv = 1.f / sm;
                wts[lane] = e0 * inv; wts[lane + 64] = e1 * inv;
            } else if (wv == 1) {
                float a = sc[128 + lane];
                float mx = a;
                #pragma unroll
                for (int m = 1; m < 64; m <<= 1) mx = fmaxf(mx, __shfl_xor(mx, m));
                float e0 = __expf(a - mx);
                float sm = e0;
                #pragma unroll
                for (int m = 1; m < 64; m <<= 1) sm += __shfl_xor(sm, m);
                wts[128 + lane] = e0 / sm;
            }
            __syncthreads();
            // ctx (threads 0..255) and wctx (threads 256..511) concurrently
            if (tid < 256) {
                float a0 = 0.f, a1 = 0.f, a2 = 0.f, a3 = 0.f;
                const ushort_t* basep = encP + ((size_t)b << 10) + tid * 4;
                #pragma unroll 8
                for (int s = 0; s < SS; ++s) {
                    float w = wts[s];
                    union { unsigned long long u; ushort_t e[4]; } v;
                    v.u = *(const unsigned long long*)(basep + ((size_t)(s * BB) << 10));
                    a0 += w * bf2f(v.e[0]); a1 += w * bf2f(v.e[1]);
                    a2 += w * bf2f(v.e[2]); a3 += w * bf2f(v.e[3]);
                }
                cx[1024 + cxp(tid * 4 + 0)] = a0; cx[1024 + cxp(tid * 4 + 1)] = a1;
                cx[1024 + cxp(tid * 4 + 2)] = a2; cx[1024 + cxp(tid * 4 + 3)] = a3;
            } else if (tid < 512) {
                int tt = tid - 256;
                float a0 = 0.f, a1 = 0.f, a2 = 0.f, a3 = 0.f;
                const ushort_t* basep = wordP + ((size_t)b << 10) + tt * 4;
                #pragma unroll 8
                for (int s = 0; s < WLW; ++s) {
                    float w = wts[128 + s];
                    union { unsigned long long u; ushort_t e[4]; } v;
                    v.u = *(const unsigned long long*)(basep + ((size_t)(s * BB) << 10));
                    a0 += w * bf2f(v.e[0]); a1 += w * bf2f(v.e[1]);
                    a2 += w * bf2f(v.e[2]); a3 += w * bf2f(v.e[3]);
                }
                cx[2048 + cxp(tt * 4 + 0)] = a0; cx[2048 + cxp(tt * 4 + 1)] = a1;
                cx[2048 + cxp(tt * 4 + 2)] = a2; cx[2048 + cxp(tt * 4 + 3)] = a3;
            }
            __syncthreads();
            // pose: chunked mapping -- lane handles elems c*1024 + lane*16 + i
            // (cx reads conflict-free via transposed blocks; W_out reads coalesced)
            float cr[48];
            #pragma unroll
            for (int c3 = 0; c3 < 3; ++c3)
                #pragma unroll
                for (int i = 0; i < 16; ++i)
                    cr[c3 * 16 + i] = cx[c3 * 1024 + (i << 6) + lane];
            int td = t - PLP;
            for (int oo = 0; oo < 9; ++oo) {
                int o = wv * 9 + oo;   // 0..143
                const ushort_t* wr = wout_p + (size_t)o * (3 * HH) + lane * 16;
                float s = 0.f;
                #pragma unroll
                for (int c3 = 0; c3 < 3; ++c3) {
                    short8 w8a = ldfrag(wr + c3 * 1024);
                    short8 w8b = ldfrag(wr + c3 * 1024 + 8);
                    #pragma unroll
                    for (int i = 0; i < 8; ++i) s += bf2f((ushort_t)w8a[i]) * cr[c3 * 16 + i];
                    #pragma unroll
                    for (int i = 0; i < 8; ++i) s += bf2f((ushort_t)w8b[i]) * cr[c3 * 16 + 8 + i];
                }
                #pragma unroll
                for (int m = 1; m < 64; m <<= 1) s += __shfl_xor(s, m);
                if (lane == 0) {
                    float v = s + ((o < OO) ? ldf(b_out, o, isbf) : 0.f);
                    if (o < OO) {
                        size_t oi = ((size_t)td * BB + b) * OO + o;
                        if (isbf) ((ushort_t*)out)[oi] = f2bf(v);
                        else      ((float*)out)[oi] = v;
                    }
                    sysst_u16(&pose_pad[(size_t)b * KP + o], (o < OO) ? f2bf(v) : (ushort_t)0);
                }
            }
        }
        ++bphase;
        gbar(flags, bphase);
    }
}

extern "C" void kernel_launch(void* const* d_in, const int* in_sizes, int n_in,
                              void* d_out, int out_size, void* d_ws, size_t ws_size,
                              hipStream_t stream)
{
    (void)in_sizes; (void)n_in; (void)out_size; (void)ws_size;
    const void* enc_states = d_in[0];
    const void* enc_hidden = d_in[1];
    const void* prev_poses = d_in[2];
    const void* words      = d_in[3];
    const void* W_ed  = d_in[5];
    const void* b_ed  = d_in[6];
    const void* W_att = d_in[7];
    const void* b_att = d_in[8];
    const void* W_watt = d_in[9];
    const void* b_watt = d_in[10];
    const void* W_ih  = d_in[11];
    const void* W_hh  = d_in[12];
    const void* b_ih  = d_in[13];
    const void* b_hh  = d_in[14];
    const void* W_out = d_in[15];
    const void* b_out = d_in[16];

    char* base = (char*)d_ws;
    size_t off = 0;
    auto alloc = [&](size_t bytes) -> char* {
        char* p = base + off;
        off = (off + bytes + 255) & ~(size_t)255;
        return p;
    };
    unsigned* flagbar  = (unsigned*)alloc(128 + (size_t)NWG * 128);  // dtype line + 64 flag lines
    ushort_t* ehcat    = (ushort_t*)alloc((size_t)BB * EE * 2);
    ushort_t* wih_p    = (ushort_t*)alloc((size_t)3 * HH * KP * 2);
    ushort_t* wout_p   = (ushort_t*)alloc((size_t)144 * 3 * HH * 2);
    ushort_t* pp_pad   = (ushort_t*)alloc((size_t)PLP * BB * KP * 2);
    ushort_t* pose_pad = (ushort_t*)alloc((size_t)BB * KP * 2);
    ushort_t* whh_bf   = (ushort_t*)alloc((size_t)3 * HH * HH * 2);
    float*    hF0      = (float*)alloc((size_t)BB * HH * 4);
    float*    hF1      = (float*)alloc((size_t)BB * HH * 4);
    ushort_t* hhi0     = (ushort_t*)alloc((size_t)BB * HH * 2);
    ushort_t* hhi1     = (ushort_t*)alloc((size_t)BB * HH * 2);
    ushort_t* hlo0     = (ushort_t*)alloc((size_t)BB * HH * 2);
    ushort_t* hlo1     = (ushort_t*)alloc((size_t)BB * HH * 2);
    // encP then wordP MUST stay adjacent: k_persist's score loop indexes both
    // through one base pointer (16 MiB encP block is 256-aligned, so wordP
    // lands exactly at encP + SS*BB*HH elements).
    ushort_t* encP     = (ushort_t*)alloc((size_t)SS * BB * HH * 2);
    ushort_t* wordP    = (ushort_t*)alloc((size_t)WLW * BB * HH * 2);

    k_detect<<<1, 256, 0, stream>>>((const unsigned*)enc_states, flagbar);

    k_prep<<<17512, 256, 0, stream>>>(enc_hidden, W_ih, W_out, prev_poses, W_hh,
                                      ehcat, wih_p, wout_p, pp_pad, pose_pad, whh_bf,
                                      flagbar);

    // h0 = ehcat @ W_ed^T + b_ed
    k_gemm<<<16, 256, 0, stream>>>(ehcat, 1, EE, EE, W_ed, 0, EE, EE, b_ed,
                                   hF0, nullptr, hhi0, hlo0, HH, BB, HH, EE, flagbar);
    // encP = enc @ W_att^T + b_att
    k_gemm<<<2048, 256, 0, stream>>>(enc_states, 0, EE, EE, W_att, 0, EE, EE, b_att,
                                     nullptr, encP, nullptr, nullptr, HH, SS * BB, HH, EE, flagbar);
    // wordP = words @ W_watt^T + b_watt
    k_gemm<<<1024, 256, 0, stream>>>(words, 0, 200, 200, W_watt, 0, 200, 200, b_watt,
                                     nullptr, wordP, nullptr, nullptr, HH, WLW * BB, HH, 224, flagbar);

    (void)hipFuncSetAttribute((const void*)k_persist,
                              hipFuncAttributeMaxDynamicSharedMemorySize, 154112);
    k_persist<<<NWG, NTH, 154112, stream>>>(encP, wordP, whh_bf, wih_p,
                                            b_ih, b_hh, wout_p, b_out, pp_pad, pose_pad,
                                            hF0, hF1, hhi0, hhi1, hlo0, hlo1,
                                            d_out, flagbar);
}